// Round 3
// baseline (708.359 us; speedup 1.0000x reference)
//
#include <hip/hip_runtime.h>

#define NB   32
#define NQL  2048
#define NKL  2048
#define DH   128
#define QBLK 64
#define KBLK 64
#define NT   (NKL / KBLK)
#define EPS  1e-6f

typedef __bf16 bf16x8 __attribute__((ext_vector_type(8)));
typedef __bf16 bf16x4 __attribute__((ext_vector_type(4)));
typedef float  f32x4  __attribute__((ext_vector_type(4)));

// ---- prefetch load/store macros: named float4 regs only, no arrays/lambdas ----
#define LOAD_K(k0) do { \
    const float* kb_ = kbase + (size_t)((k0) + rK) * DH + cK;            \
    ka0 = *(const float4*)(kb_ +  0);  ka1 = *(const float4*)(kb_ +  4); \
    ka2 = *(const float4*)(kb_ +  8);  ka3 = *(const float4*)(kb_ + 12); \
    ka4 = *(const float4*)(kb_ + 16);  ka5 = *(const float4*)(kb_ + 20); \
    ka6 = *(const float4*)(kb_ + 24);  ka7 = *(const float4*)(kb_ + 28); \
} while (0)

#define LOAD_V(k0) do { \
    const float* vb_ = vbase + (size_t)((k0) + khV * 32) * DH + dV;               \
    va0 = make_float4(vb_[ 0*DH], vb_[ 1*DH], vb_[ 2*DH], vb_[ 3*DH]);            \
    va1 = make_float4(vb_[ 4*DH], vb_[ 5*DH], vb_[ 6*DH], vb_[ 7*DH]);            \
    va2 = make_float4(vb_[ 8*DH], vb_[ 9*DH], vb_[10*DH], vb_[11*DH]);            \
    va3 = make_float4(vb_[12*DH], vb_[13*DH], vb_[14*DH], vb_[15*DH]);            \
    va4 = make_float4(vb_[16*DH], vb_[17*DH], vb_[18*DH], vb_[19*DH]);            \
    va5 = make_float4(vb_[20*DH], vb_[21*DH], vb_[22*DH], vb_[23*DH]);            \
    va6 = make_float4(vb_[24*DH], vb_[25*DH], vb_[26*DH], vb_[27*DH]);            \
    va7 = make_float4(vb_[28*DH], vb_[29*DH], vb_[30*DH], vb_[31*DH]);            \
} while (0)

#define LOAD_M(k0) do { \
    const float* mb_ = mbase + (k0) + lg * 4;       \
    mk0 = *(const float4*)(mb_ +  0);               \
    mk1 = *(const float4*)(mb_ + 16);               \
    mk2 = *(const float4*)(mb_ + 32);               \
    mk3 = *(const float4*)(mb_ + 48);               \
} while (0)

#define STG_K(A, B, OFF) \
    *(bf16x8*)&Ks[rK * 128 + ((cK + (OFF)) ^ swzK)] = (bf16x8){ \
        (__bf16)A.x, (__bf16)A.y, (__bf16)A.z, (__bf16)A.w,     \
        (__bf16)B.x, (__bf16)B.y, (__bf16)B.z, (__bf16)B.w }

#define STG_V(A, B, OFF) \
    *(bf16x8*)&Vs[dV * 64 + (((khV << 5) + (OFF)) ^ swzV)] = (bf16x8){ \
        (__bf16)A.x, (__bf16)A.y, (__bf16)A.z, (__bf16)A.w,            \
        (__bf16)B.x, (__bf16)B.y, (__bf16)B.z, (__bf16)B.w }

// One block = one (batch, 64-row Q tile). 4 waves; wave w owns q rows [w*16, w*16+16).
// Swapped QK^T: S^T = K·Q^T so lane's lq = q; softmax state is lane-local in k.
// Pipeline: named regs hold tile kt+1's f32 K/V/mask (issued right after staging
// barrier of tile kt); converted+written to LDS at tile kt+1's staging phase.
__global__ __launch_bounds__(256, 3) void
attn_kernel(const float* __restrict__ Qg, const float* __restrict__ Kg,
            const float* __restrict__ Vg, const float* __restrict__ Mg,
            float* __restrict__ Og)
{
    // XCD swizzle: 1024 wgs, 8 XCDs -> each XCD gets 4 whole batches (K/V L2 reuse)
    const int wg = ((blockIdx.x & 7) << 7) | (blockIdx.x >> 3);
    const int b  = wg >> 5;
    const int q0 = (wg & 31) * QBLK;

    const int t  = threadIdx.x;
    const int w  = t >> 6;
    const int l  = t & 63;
    const int lq = l & 15;
    const int lg = l >> 4;

    __shared__ __align__(16) unsigned short Ks[64 * 128];   // [k][d] bf16, XOR-swizzled
    __shared__ __align__(16) unsigned short Vs[128 * 64];   // [d][k] bf16, XOR-swizzled
    __shared__ __align__(16) unsigned short Ps[4][16][72];  // per-wave P[q][k]

    const int rK   = t >> 2;           // K row 0..63
    const int cK   = (t & 3) * 32;     // K col (d) base
    const int dV   = t >> 1;           // V d-row 0..127
    const int khV  = t & 1;            // V k-half
    const int swzK = (rK & 7) << 3;
    const int swzV = (dV & 7) << 3;
    const int swzL = (lq & 7) << 3;    // read-side swizzle

    const int qrow = q0 + w * 16 + lq;

    // Q fragment (B-operand: lane holds Q[qrow][c*32 + lg*8 + j])
    bf16x8 qf[4];
    {
        const float* qb = Qg + ((size_t)b * NQL + qrow) * DH;
        #pragma unroll
        for (int c = 0; c < 4; ++c) {
            const float* p = qb + c * 32 + lg * 8;
            float4 x = *(const float4*)(p);
            float4 y = *(const float4*)(p + 4);
            qf[c] = (bf16x8){ (__bf16)x.x, (__bf16)x.y, (__bf16)x.z, (__bf16)x.w,
                              (__bf16)y.x, (__bf16)y.y, (__bf16)y.z, (__bf16)y.w };
        }
    }

    float m_run = -1e30f, z_part = 0.f, s_part = 0.f;
    f32x4 oacc[8];
    #pragma unroll
    for (int n = 0; n < 8; ++n) oacc[n] = (f32x4){0.f, 0.f, 0.f, 0.f};

    // named prefetch registers
    float4 ka0, ka1, ka2, ka3, ka4, ka5, ka6, ka7;
    float4 va0, va1, va2, va3, va4, va5, va6, va7;
    float4 mk0, mk1, mk2, mk3;

    const float* kbase = Kg + (size_t)b * NKL * DH;
    const float* vbase = Vg + (size_t)b * NKL * DH;
    const float* mbase = Mg + ((size_t)b * NQL + qrow) * NKL;

    LOAD_K(0);
    LOAD_V(0);
    LOAD_M(0);

    const float scale = 0.08838834764831845f;   // 1/sqrt(128)

    for (int kt = 0; kt < NT; ++kt) {
        __syncthreads();   // all waves done reading LDS of tile kt-1

        // ---- staging: convert held regs -> bf16 LDS ----
        STG_K(ka0, ka1,  0);  STG_K(ka2, ka3,  8);
        STG_K(ka4, ka5, 16);  STG_K(ka6, ka7, 24);
        STG_V(va0, va1,  0);  STG_V(va2, va3,  8);
        STG_V(va4, va5, 16);  STG_V(va6, va7, 24);

        // mask regs are consumed this tile's softmax: move to locals now
        float mkf[16];
        mkf[ 0]=mk0.x; mkf[ 1]=mk0.y; mkf[ 2]=mk0.z; mkf[ 3]=mk0.w;
        mkf[ 4]=mk1.x; mkf[ 5]=mk1.y; mkf[ 6]=mk1.z; mkf[ 7]=mk1.w;
        mkf[ 8]=mk2.x; mkf[ 9]=mk2.y; mkf[10]=mk2.z; mkf[11]=mk2.w;
        mkf[12]=mk3.x; mkf[13]=mk3.y; mkf[14]=mk3.z; mkf[15]=mk3.w;

        __syncthreads();

        // ---- issue next tile's loads; latency hides under compute ----
        if (kt + 1 < NT) {
            const int kn = (kt + 1) * KBLK;
            LOAD_K(kn);
            LOAD_V(kn);
            LOAD_M(kn);
        }

        // ---- S^T = K·Q^T ----
        f32x4 sacc[4];
        #pragma unroll
        for (int m = 0; m < 4; ++m) sacc[m] = (f32x4){0.f, 0.f, 0.f, 0.f};
        __builtin_amdgcn_s_setprio(1);
        #pragma unroll
        for (int m = 0; m < 4; ++m) {
            #pragma unroll
            for (int c = 0; c < 4; ++c) {
                bf16x8 af = *(bf16x8*)&Ks[(m * 16 + lq) * 128 + ((c * 32 + lg * 8) ^ swzL)];
                sacc[m] = __builtin_amdgcn_mfma_f32_16x16x32_bf16(af, qf[c], sacc[m], 0, 0, 0);
            }
        }
        __builtin_amdgcn_s_setprio(0);

        // ---- online softmax (lane owns 16 scores of q=qrow) ----
        float sv[4][4], tmax = -1e30f;
        #pragma unroll
        for (int m = 0; m < 4; ++m)
            #pragma unroll
            for (int r = 0; r < 4; ++r) {
                sv[m][r] = sacc[m][r] * scale;
                tmax = fmaxf(tmax, sv[m][r]);
            }
        tmax = fmaxf(tmax, __shfl_xor(tmax, 16));
        tmax = fmaxf(tmax, __shfl_xor(tmax, 32));

        // T13 defer-max: skip rescale unless max grew past threshold
        if (!__all(tmax - m_run <= 8.f)) {
            const float mnew  = fmaxf(m_run, tmax);
            const float alpha = __expf(m_run - mnew);
            m_run = mnew;
            z_part *= alpha;
            s_part *= alpha;
            float alr[4];
            #pragma unroll
            for (int r = 0; r < 4; ++r) alr[r] = __shfl(alpha, lg * 4 + r);
            #pragma unroll
            for (int n = 0; n < 8; ++n)
                #pragma unroll
                for (int r = 0; r < 4; ++r) oacc[n][r] *= alr[r];
        }

        float zl = 0.f, sl = 0.f, pm[4][4];
        #pragma unroll
        for (int m = 0; m < 4; ++m)
            #pragma unroll
            for (int r = 0; r < 4; ++r) {
                float p  = __expf(sv[m][r] - m_run);   // bounded by e^8
                zl += p;
                float pq = p * mkf[m * 4 + r];
                sl += pq;
                pm[m][r] = pq;
            }
        z_part += zl;
        s_part += sl;

        // P -> per-wave LDS (b64 writes)
        #pragma unroll
        for (int m = 0; m < 4; ++m) {
            *(bf16x4*)&Ps[w][lq][m * 16 + lg * 4] =
                (bf16x4){ (__bf16)pm[m][0], (__bf16)pm[m][1],
                          (__bf16)pm[m][2], (__bf16)pm[m][3] };
        }

        // ---- O += P·V ----
        __builtin_amdgcn_s_setprio(1);
        #pragma unroll
        for (int kc = 0; kc < 2; ++kc) {
            bf16x8 pa = *(bf16x8*)&Ps[w][lq][kc * 32 + lg * 8];
            #pragma unroll
            for (int n = 0; n < 8; ++n) {
                bf16x8 vv = *(bf16x8*)&Vs[(n * 16 + lq) * 64 + ((kc * 32 + lg * 8) ^ swzL)];
                oacc[n] = __builtin_amdgcn_mfma_f32_16x16x32_bf16(pa, vv, oacc[n], 0, 0, 0);
            }
        }
        __builtin_amdgcn_s_setprio(0);
    }

    // epilogue: finish cross-lane Z/S reduction, divide, store
    float z = z_part + __shfl_xor(z_part, 16);
    z += __shfl_xor(z, 32);
    float s = s_part + __shfl_xor(s_part, 16);
    s += __shfl_xor(s, 32);
    const float inv = 1.f / (s + EPS * z);
    float ivr[4];
    #pragma unroll
    for (int r = 0; r < 4; ++r) ivr[r] = __shfl(inv, lg * 4 + r);

    float* ob = Og + ((size_t)b * NQL + q0 + w * 16) * DH;
    #pragma unroll
    for (int n = 0; n < 8; ++n)
        #pragma unroll
        for (int r = 0; r < 4; ++r)
            ob[(size_t)(lg * 4 + r) * DH + n * 16 + lq] = oacc[n][r] * ivr[r];
}

extern "C" void kernel_launch(void* const* d_in, const int* in_sizes, int n_in,
                              void* d_out, int out_size, void* d_ws, size_t ws_size,
                              hipStream_t stream)
{
    const float* Q = (const float*)d_in[0];
    const float* K = (const float*)d_in[1];
    const float* V = (const float*)d_in[2];
    const float* M = (const float*)d_in[3];
    float* O = (float*)d_out;
    dim3 grid(NB * (NQL / QBLK));   // 1024
    attn_kernel<<<grid, 256, 0, stream>>>(Q, K, V, M, O);
}

// Round 5
// 195.336 us; speedup vs baseline: 3.6264x; 3.6264x over previous
//
#include <hip/hip_runtime.h>

#define NB   32
#define NQL  2048
#define NKL  2048
#define DH   128
#define QBLK 64
#define KBLK 64
#define NT   (NKL / KBLK)
#define EPS  1e-6f

typedef __bf16 bf16x8 __attribute__((ext_vector_type(8)));
typedef __bf16 bf16x4 __attribute__((ext_vector_type(4)));
typedef float  f32x4  __attribute__((ext_vector_type(4)));

// ======================= prep: K -> swizzled bf16 tile images =======================
// Image for (b,kt) is the exact 16KB LDS content: img[rK*128 + x] = K[64kt+rK][x ^ ((rK&7)<<3)]
__global__ __launch_bounds__(256) void
prep_k(const float* __restrict__ Kg, unsigned short* __restrict__ Kimg)
{
    const int blk = blockIdx.x;            // b*32 + kt
    const int t   = threadIdx.x;
    const int rK  = t >> 2;
    const int x0  = (t & 3) * 32;
    const int swz = (rK & 7) << 3;
    const float* src = Kg + ((size_t)blk * 64 + rK) * DH;
    unsigned short* dst = Kimg + ((size_t)blk << 13) + rK * 128;
    #pragma unroll
    for (int i = 0; i < 4; ++i) {
        const int c0 = (x0 + i * 8) ^ swz;       // 8-aligned
        float4 a = *(const float4*)(src + c0);
        float4 c = *(const float4*)(src + c0 + 4);
        *(bf16x8*)(dst + x0 + i * 8) =
            (bf16x8){ (__bf16)a.x, (__bf16)a.y, (__bf16)a.z, (__bf16)a.w,
                      (__bf16)c.x, (__bf16)c.y, (__bf16)c.z, (__bf16)c.w };
    }
}

// ============== prep: V -> transposed swizzled bf16 tile images ==============
// img[dV*64 + y] = V[64kt + (y ^ ((dV&7)<<3))][dV]
__global__ __launch_bounds__(256) void
prep_v(const float* __restrict__ Vg, unsigned short* __restrict__ Vimg)
{
    __shared__ float T[64 * 132];
    const int blk = blockIdx.x;            // b*32 + kt
    const int t   = threadIdx.x;
    {
        const int r  = t >> 2;
        const int c0 = (t & 3) * 32;
        const float* src = Vg + ((size_t)blk * 64 + r) * DH + c0;
        #pragma unroll
        for (int j = 0; j < 8; ++j)
            *(float4*)&T[r * 132 + c0 + j * 4] = *(const float4*)(src + j * 4);
    }
    __syncthreads();
    {
        const int dV  = t >> 1;
        const int yh  = (t & 1) * 32;
        const int swz = (dV & 7) << 3;
        unsigned short* dst = Vimg + ((size_t)blk << 13) + dV * 64 + yh;
        #pragma unroll
        for (int i = 0; i < 4; ++i) {
            const int ks = (yh + i * 8) ^ swz;   // 8-aligned, contiguous k-run
            bf16x8 o;
            #pragma unroll
            for (int j = 0; j < 8; ++j) o[j] = (__bf16)T[(ks + j) * 132 + dV];
            *(bf16x8*)(dst + i * 8) = o;
        }
    }
}

// =============================== main kernel ===============================
#define GLL16(GSRC, LDST) \
    __builtin_amdgcn_global_load_lds( \
        (const __attribute__((address_space(1))) void*)(GSRC), \
        (__attribute__((address_space(3))) void*)(LDST), 16, 0, 0)

// stage 16KB tile image -> LDS buffer: wave w copies bytes [w*4KB, w*4KB+4KB)
#define ISSUE_KV(KT, KB, VB) do { \
    const size_t tb_ = ((size_t)(b * 32 + (KT))) << 14;               /* bytes */ \
    const char* ksrc_ = (const char*)KimgB + tb_ + woff + lby;                    \
    const char* vsrc_ = (const char*)VimgB + tb_ + woff + lby;                    \
    char* kd_ = (char*)(KB) + woff;                                               \
    char* vd_ = (char*)(VB) + woff;                                               \
    GLL16(ksrc_ +    0, kd_ +    0);  GLL16(ksrc_ + 1024, kd_ + 1024);            \
    GLL16(ksrc_ + 2048, kd_ + 2048);  GLL16(ksrc_ + 3072, kd_ + 3072);            \
    GLL16(vsrc_ +    0, vd_ +    0);  GLL16(vsrc_ + 1024, vd_ + 1024);            \
    GLL16(vsrc_ + 2048, vd_ + 2048);  GLL16(vsrc_ + 3072, vd_ + 3072);            \
} while (0)

#define LOAD_M(K0, R0, R1, R2, R3) do { \
    const float* mb_ = mbase + (K0) + lg * 4; \
    R0 = *(const float4*)(mb_ +  0);  R1 = *(const float4*)(mb_ + 16); \
    R2 = *(const float4*)(mb_ + 32);  R3 = *(const float4*)(mb_ + 48); \
} while (0)

#define COMPUTE(KB, VB, M0, M1, M2, M3) do { \
    f32x4 sacc[4]; \
    _Pragma("unroll") for (int m = 0; m < 4; ++m) sacc[m] = (f32x4){0.f,0.f,0.f,0.f}; \
    __builtin_amdgcn_s_setprio(1); \
    _Pragma("unroll") for (int m = 0; m < 4; ++m) { \
        _Pragma("unroll") for (int c = 0; c < 4; ++c) { \
            bf16x8 af = *(bf16x8*)&KB[(m * 16 + lq) * 128 + ((c * 32 + lg * 8) ^ swzL)]; \
            sacc[m] = __builtin_amdgcn_mfma_f32_16x16x32_bf16(af, qf[c], sacc[m], 0, 0, 0); \
        } \
    } \
    __builtin_amdgcn_s_setprio(0); \
    float mk_[16] = { M0.x, M0.y, M0.z, M0.w,  M1.x, M1.y, M1.z, M1.w, \
                      M2.x, M2.y, M2.z, M2.w,  M3.x, M3.y, M3.z, M3.w }; \
    float sv[4][4], tmax = -1e30f; \
    _Pragma("unroll") for (int m = 0; m < 4; ++m) \
        _Pragma("unroll") for (int r = 0; r < 4; ++r) { \
            sv[m][r] = sacc[m][r] * scale; \
            tmax = fmaxf(tmax, sv[m][r]); \
        } \
    tmax = fmaxf(tmax, __shfl_xor(tmax, 16)); \
    tmax = fmaxf(tmax, __shfl_xor(tmax, 32)); \
    if (!__all(tmax - m_run <= 8.f)) { \
        const float mnew  = fmaxf(m_run, tmax); \
        const float alpha = __expf(m_run - mnew); \
        m_run = mnew;  z_part *= alpha;  s_part *= alpha; \
        float alr[4]; \
        _Pragma("unroll") for (int r = 0; r < 4; ++r) alr[r] = __shfl(alpha, lg * 4 + r); \
        _Pragma("unroll") for (int n = 0; n < 8; ++n) \
            _Pragma("unroll") for (int r = 0; r < 4; ++r) oacc[n][r] *= alr[r]; \
    } \
    float zl = 0.f, sl = 0.f, pm[4][4]; \
    _Pragma("unroll") for (int m = 0; m < 4; ++m) \
        _Pragma("unroll") for (int r = 0; r < 4; ++r) { \
            float p = __expf(sv[m][r] - m_run); \
            zl += p; \
            float pq = p * mk_[m * 4 + r]; \
            sl += pq;  pm[m][r] = pq; \
        } \
    z_part += zl;  s_part += sl; \
    _Pragma("unroll") for (int m = 0; m < 4; ++m) \
        *(bf16x4*)&Ps[w][lq][m * 16 + lg * 4] = \
            (bf16x4){ (__bf16)pm[m][0], (__bf16)pm[m][1], (__bf16)pm[m][2], (__bf16)pm[m][3] }; \
    __builtin_amdgcn_s_setprio(1); \
    _Pragma("unroll") for (int kc = 0; kc < 2; ++kc) { \
        bf16x8 pa = *(bf16x8*)&Ps[w][lq][kc * 32 + lg * 8]; \
        _Pragma("unroll") for (int n = 0; n < 8; ++n) { \
            bf16x8 vv = *(bf16x8*)&VB[(n * 16 + lq) * 64 + ((kc * 32 + lg * 8) ^ swzL)]; \
            oacc[n] = __builtin_amdgcn_mfma_f32_16x16x32_bf16(pa, vv, oacc[n], 0, 0, 0); \
        } \
    } \
    __builtin_amdgcn_s_setprio(0); \
} while (0)

// T3 minimal 2-phase: issue next-tile loads FIRST, compute current, then one
// __syncthreads (vmcnt(0)+lgkmcnt(0)+barrier) per tile. WAR-safe: buffer NXT
// was last read in iter kt-1, which ended with this barrier. LAST literal 0/1.
#define ITER(KT, KBc, VBc, KBn, VBn, MU0,MU1,MU2,MU3, ML0,ML1,ML2,ML3, LAST) do { \
    if (!(LAST)) { \
        ISSUE_KV((KT) + 1, KBn, VBn); \
        LOAD_M(((KT) + 1) * KBLK, ML0, ML1, ML2, ML3); \
    } \
    __builtin_amdgcn_sched_barrier(0); \
    COMPUTE(KBc, VBc, MU0, MU1, MU2, MU3); \
    if (!(LAST)) __syncthreads(); \
} while (0)

__global__ __launch_bounds__(256, 2) void
attn_main(const float* __restrict__ Qg, const unsigned short* __restrict__ Kimg,
          const unsigned short* __restrict__ Vimg, const float* __restrict__ Mg,
          float* __restrict__ Og)
{
    const int wg = ((blockIdx.x & 7) << 7) | (blockIdx.x >> 3);   // XCD swizzle
    const int b  = wg >> 5;
    const int q0 = (wg & 31) * QBLK;

    const int t  = threadIdx.x;
    const int w  = t >> 6;
    const int l  = t & 63;
    const int lq = l & 15;
    const int lg = l >> 4;
    const int swzL = (lq & 7) << 3;
    const int woff = w * 4096;        // staging byte offset per wave
    const int lby  = l * 16;          // lane byte offset within wave's 1KB chunk

    __shared__ __align__(16) unsigned short Kb0[64 * 128];
    __shared__ __align__(16) unsigned short Kb1[64 * 128];
    __shared__ __align__(16) unsigned short Vb0[128 * 64];
    __shared__ __align__(16) unsigned short Vb1[128 * 64];
    __shared__ __align__(16) unsigned short Ps[4][16][72];

    const char* KimgB = (const char*)Kimg;
    const char* VimgB = (const char*)Vimg;

    const int qrow = q0 + w * 16 + lq;

    bf16x8 qf[4];
    {
        const float* qb = Qg + ((size_t)b * NQL + qrow) * DH;
        #pragma unroll
        for (int c = 0; c < 4; ++c) {
            const float* p = qb + c * 32 + lg * 8;
            float4 x = *(const float4*)(p);
            float4 y = *(const float4*)(p + 4);
            qf[c] = (bf16x8){ (__bf16)x.x, (__bf16)x.y, (__bf16)x.z, (__bf16)x.w,
                              (__bf16)y.x, (__bf16)y.y, (__bf16)y.z, (__bf16)y.w };
        }
    }

    float m_run = -1e30f, z_part = 0.f, s_part = 0.f;
    f32x4 oacc[8];
    #pragma unroll
    for (int n = 0; n < 8; ++n) oacc[n] = (f32x4){0.f, 0.f, 0.f, 0.f};

    const float* mbase = Mg + ((size_t)b * NQL + qrow) * NKL;
    const float scale = 0.08838834764831845f;

    float4 mA0, mA1, mA2, mA3, mB0, mB1, mB2, mB3;

    // prologue: tile 0 staged + drained
    ISSUE_KV(0, Kb0, Vb0);
    LOAD_M(0, mA0, mA1, mA2, mA3);
    __syncthreads();

    for (int kt = 0; kt < NT - 2; kt += 2) {
        ITER(kt,     Kb0, Vb0, Kb1, Vb1, mA0,mA1,mA2,mA3, mB0,mB1,mB2,mB3, 0);
        ITER(kt + 1, Kb1, Vb1, Kb0, Vb0, mB0,mB1,mB2,mB3, mA0,mA1,mA2,mA3, 0);
    }
    ITER(NT - 2, Kb0, Vb0, Kb1, Vb1, mA0,mA1,mA2,mA3, mB0,mB1,mB2,mB3, 0);
    ITER(NT - 1, Kb1, Vb1, Kb0, Vb0, mB0,mB1,mB2,mB3, mA0,mA1,mA2,mA3, 1);

    // epilogue
    float z = z_part + __shfl_xor(z_part, 16);
    z += __shfl_xor(z, 32);
    float s = s_part + __shfl_xor(s_part, 16);
    s += __shfl_xor(s, 32);
    const float inv = 1.f / (s + EPS * z);
    float ivr[4];
    #pragma unroll
    for (int r = 0; r < 4; ++r) ivr[r] = __shfl(inv, lg * 4 + r);

    float* ob = Og + ((size_t)b * NQL + q0 + w * 16) * DH;
    #pragma unroll
    for (int n = 0; n < 8; ++n)
        #pragma unroll
        for (int r = 0; r < 4; ++r)
            ob[(size_t)(lg * 4 + r) * DH + n * 16 + lq] = oacc[n][r] * ivr[r];
}

// =============================== fallback (round-3 kernel) ===============================
__global__ __launch_bounds__(256, 3) void
attn_fb(const float* __restrict__ Qg, const float* __restrict__ Kg,
        const float* __restrict__ Vg, const float* __restrict__ Mg,
        float* __restrict__ Og)
{
    const int wg = ((blockIdx.x & 7) << 7) | (blockIdx.x >> 3);
    const int b  = wg >> 5;
    const int q0 = (wg & 31) * QBLK;
    const int t  = threadIdx.x;
    const int w  = t >> 6;
    const int l  = t & 63;
    const int lq = l & 15;
    const int lg = l >> 4;
    __shared__ __align__(16) unsigned short Ks[64 * 128];
    __shared__ __align__(16) unsigned short Vs[128 * 64];
    __shared__ __align__(16) unsigned short Ps[4][16][72];
    const int rK   = t >> 2;
    const int cK   = (t & 3) * 32;
    const int dV   = t >> 1;
    const int khV  = t & 1;
    const int swzK = (rK & 7) << 3;
    const int swzV = (dV & 7) << 3;
    const int swzL = (lq & 7) << 3;
    const int qrow = q0 + w * 16 + lq;
    bf16x8 qf[4];
    {
        const float* qb = Qg + ((size_t)b * NQL + qrow) * DH;
        #pragma unroll
        for (int c = 0; c < 4; ++c) {
            const float* p = qb + c * 32 + lg * 8;
            float4 x = *(const float4*)(p);
            float4 y = *(const float4*)(p + 4);
            qf[c] = (bf16x8){ (__bf16)x.x, (__bf16)x.y, (__bf16)x.z, (__bf16)x.w,
                              (__bf16)y.x, (__bf16)y.y, (__bf16)y.z, (__bf16)y.w };
        }
    }
    float m_run = -1e30f, z_part = 0.f, s_part = 0.f;
    f32x4 oacc[8];
    #pragma unroll
    for (int n = 0; n < 8; ++n) oacc[n] = (f32x4){0.f, 0.f, 0.f, 0.f};
    const float* kbase = Kg + (size_t)b * NKL * DH;
    const float* vbase = Vg + (size_t)b * NKL * DH;
    const float* mbase = Mg + ((size_t)b * NQL + qrow) * NKL;
    const float scale = 0.08838834764831845f;
    for (int kt = 0; kt < NT; ++kt) {
        const int k0 = kt * KBLK;
        float mkf[16];
        {
            const float* mb = mbase + k0 + lg * 4;
            #pragma unroll
            for (int m = 0; m < 4; ++m) {
                float4 x = *(const float4*)(mb + m * 16);
                mkf[m*4+0]=x.x; mkf[m*4+1]=x.y; mkf[m*4+2]=x.z; mkf[m*4+3]=x.w;
            }
        }
        __syncthreads();
        {
            const float* kb = kbase + (size_t)(k0 + rK) * DH + cK;
            #pragma unroll
            for (int i = 0; i < 4; ++i) {
                float4 a = *(const float4*)(kb + i * 8);
                float4 c = *(const float4*)(kb + i * 8 + 4);
                *(bf16x8*)&Ks[rK * 128 + ((cK + i * 8) ^ swzK)] =
                    (bf16x8){ (__bf16)a.x, (__bf16)a.y, (__bf16)a.z, (__bf16)a.w,
                              (__bf16)c.x, (__bf16)c.y, (__bf16)c.z, (__bf16)c.w };
            }
            const float* vb = vbase + (size_t)(k0 + khV * 32) * DH + dV;
            #pragma unroll
            for (int i = 0; i < 4; ++i) {
                bf16x8 o;
                #pragma unroll
                for (int j = 0; j < 8; ++j) o[j] = (__bf16)vb[(i * 8 + j) * DH];
                *(bf16x8*)&Vs[dV * 64 + (((khV << 5) + i * 8) ^ swzV)] = o;
            }
        }
        __syncthreads();
        f32x4 sacc[4];
        #pragma unroll
        for (int m = 0; m < 4; ++m) sacc[m] = (f32x4){0.f,0.f,0.f,0.f};
        #pragma unroll
        for (int m = 0; m < 4; ++m)
            #pragma unroll
            for (int c = 0; c < 4; ++c) {
                bf16x8 af = *(bf16x8*)&Ks[(m * 16 + lq) * 128 + ((c * 32 + lg * 8) ^ swzL)];
                sacc[m] = __builtin_amdgcn_mfma_f32_16x16x32_bf16(af, qf[c], sacc[m], 0, 0, 0);
            }
        float sv[4][4], tmax = -1e30f;
        #pragma unroll
        for (int m = 0; m < 4; ++m)
            #pragma unroll
            for (int r = 0; r < 4; ++r) {
                sv[m][r] = sacc[m][r] * scale;
                tmax = fmaxf(tmax, sv[m][r]);
            }
        tmax = fmaxf(tmax, __shfl_xor(tmax, 16));
        tmax = fmaxf(tmax, __shfl_xor(tmax, 32));
        if (!__all(tmax - m_run <= 8.f)) {
            const float mnew  = fmaxf(m_run, tmax);
            const float alpha = __expf(m_run - mnew);
            m_run = mnew; z_part *= alpha; s_part *= alpha;
            float alr[4];
            #pragma unroll
            for (int r = 0; r < 4; ++r) alr[r] = __shfl(alpha, lg * 4 + r);
            #pragma unroll
            for (int n = 0; n < 8; ++n)
                #pragma unroll
                for (int r = 0; r < 4; ++r) oacc[n][r] *= alr[r];
        }
        float zl = 0.f, sl = 0.f, pm[4][4];
        #pragma unroll
        for (int m = 0; m < 4; ++m)
            #pragma unroll
            for (int r = 0; r < 4; ++r) {
                float p = __expf(sv[m][r] - m_run);
                zl += p;
                float pq = p * mkf[m * 4 + r];
                sl += pq; pm[m][r] = pq;
            }
        z_part += zl; s_part += sl;
        #pragma unroll
        for (int m = 0; m < 4; ++m)
            *(bf16x4*)&Ps[w][lq][m * 16 + lg * 4] =
                (bf16x4){ (__bf16)pm[m][0], (__bf16)pm[m][1], (__bf16)pm[m][2], (__bf16)pm[m][3] };
        #pragma unroll
        for (int kc = 0; kc < 2; ++kc) {
            bf16x8 pa = *(bf16x8*)&Ps[w][lq][kc * 32 + lg * 8];
            #pragma unroll
            for (int n = 0; n < 8; ++n) {
                bf16x8 vv = *(bf16x8*)&Vs[(n * 16 + lq) * 64 + ((kc * 32 + lg * 8) ^ swzL)];
                oacc[n] = __builtin_amdgcn_mfma_f32_16x16x32_bf16(pa, vv, oacc[n], 0, 0, 0);
            }
        }
    }
    float z = z_part + __shfl_xor(z_part, 16);
    z += __shfl_xor(z, 32);
    float s = s_part + __shfl_xor(s_part, 16);
    s += __shfl_xor(s, 32);
    const float inv = 1.f / (s + EPS * z);
    float ivr[4];
    #pragma unroll
    for (int r = 0; r < 4; ++r) ivr[r] = __shfl(inv, lg * 4 + r);
    float* ob = Og + ((size_t)b * NQL + q0 + w * 16) * DH;
    #pragma unroll
    for (int n = 0; n < 8; ++n)
        #pragma unroll
        for (int r = 0; r < 4; ++r)
            ob[(size_t)(lg * 4 + r) * DH + n * 16 + lq] = oacc[n][r] * ivr[r];
}

extern "C" void kernel_launch(void* const* d_in, const int* in_sizes, int n_in,
                              void* d_out, int out_size, void* d_ws, size_t ws_size,
                              hipStream_t stream)
{
    (void)in_sizes; (void)n_in; (void)out_size;
    const float* Q = (const float*)d_in[0];
    const float* K = (const float*)d_in[1];
    const float* V = (const float*)d_in[2];
    const float* M = (const float*)d_in[3];
    float* O = (float*)d_out;

    const size_t imgElems = (size_t)NB * NKL * DH;           // 8.39M shorts each
    const size_t need     = 2 * imgElems * sizeof(unsigned short);

    if (ws_size >= need) {
        unsigned short* Kimg = (unsigned short*)d_ws;
        unsigned short* Vimg = Kimg + imgElems;
        prep_k<<<dim3(NB * NT), 256, 0, stream>>>(K, Kimg);
        prep_v<<<dim3(NB * NT), 256, 0, stream>>>(V, Vimg);
        attn_main<<<dim3(NB * (NQL / QBLK)), 256, 0, stream>>>(Q, Kimg, Vimg, M, O);
    } else {
        attn_fb<<<dim3(NB * (NQL / QBLK)), 256, 0, stream>>>(Q, K, V, M, O);
    }
}

// Round 6
// 193.743 us; speedup vs baseline: 3.6562x; 1.0082x over previous
//
#include <hip/hip_runtime.h>

#define NB   32
#define NQL  2048
#define NKL  2048
#define DH   128
#define QBLK 64
#define KBLK 64
#define NT   (NKL / KBLK)
#define EPS  1e-6f

typedef __bf16 bf16x8 __attribute__((ext_vector_type(8)));
typedef __bf16 bf16x4 __attribute__((ext_vector_type(4)));
typedef float  f32x4  __attribute__((ext_vector_type(4)));

// ================= fused prep: K and V^T -> swizzled bf16 tile images =================
// K image (b,kt): img[rK*128 + x] = K[64kt+rK][x ^ ((rK&7)<<3)]
// V image (b,kt): img[dV*64  + y] = V[64kt + (y ^ ((dV&7)<<3))][dV]
__global__ __launch_bounds__(256) void
prep_kv(const float* __restrict__ Kg, const float* __restrict__ Vg,
        unsigned short* __restrict__ Kimg, unsigned short* __restrict__ Vimg)
{
    __shared__ float T[64 * 132];
    const int t = threadIdx.x;
    if (blockIdx.x < NB * NT) {
        const int blk = blockIdx.x;
        const int rK  = t >> 2;
        const int x0  = (t & 3) * 32;
        const int swz = (rK & 7) << 3;
        const float* src = Kg + ((size_t)blk * 64 + rK) * DH;
        unsigned short* dst = Kimg + ((size_t)blk << 13) + rK * 128;
        #pragma unroll
        for (int i = 0; i < 4; ++i) {
            const int c0 = (x0 + i * 8) ^ swz;
            float4 a = *(const float4*)(src + c0);
            float4 c = *(const float4*)(src + c0 + 4);
            *(bf16x8*)(dst + x0 + i * 8) =
                (bf16x8){ (__bf16)a.x, (__bf16)a.y, (__bf16)a.z, (__bf16)a.w,
                          (__bf16)c.x, (__bf16)c.y, (__bf16)c.z, (__bf16)c.w };
        }
    } else {
        const int blk = blockIdx.x - NB * NT;
        {
            const int r  = t >> 2;
            const int c0 = (t & 3) * 32;
            const float* src = Vg + ((size_t)blk * 64 + r) * DH + c0;
            #pragma unroll
            for (int j = 0; j < 8; ++j)
                *(float4*)&T[r * 132 + c0 + j * 4] = *(const float4*)(src + j * 4);
        }
        __syncthreads();
        {
            const int dV  = t >> 1;
            const int yh  = (t & 1) * 32;
            const int swz = (dV & 7) << 3;
            unsigned short* dst = Vimg + ((size_t)blk << 13) + dV * 64 + yh;
            #pragma unroll
            for (int i = 0; i < 4; ++i) {
                const int ks = (yh + i * 8) ^ swz;
                bf16x8 o;
                #pragma unroll
                for (int j = 0; j < 8; ++j) o[j] = (__bf16)T[(ks + j) * 132 + dV];
                *(bf16x8*)(dst + i * 8) = o;
            }
        }
    }
}

// =============================== main kernel ===============================
// T14 reg-staging: named regs ik0..3 / iv0..3 hold tile KT+1's image quarter.
// Iter kt: ds_write img(kt+1) -> buf_other; load img(kt+2) -> regs;
// compute(kt) on buf_cur; lgkmcnt(0)+s_barrier (NO vmcnt drain -> ~2-iter load slack).

#define LOAD_IMG(KT) do { \
    const char* ks_ = KimgB + (((size_t)(b * 32 + (KT))) << 14) + woff + lby; \
    const char* vs_ = VimgB + (((size_t)(b * 32 + (KT))) << 14) + woff + lby; \
    ik0 = *(const bf16x8*)(ks_ +    0);  ik1 = *(const bf16x8*)(ks_ + 1024); \
    ik2 = *(const bf16x8*)(ks_ + 2048);  ik3 = *(const bf16x8*)(ks_ + 3072); \
    iv0 = *(const bf16x8*)(vs_ +    0);  iv1 = *(const bf16x8*)(vs_ + 1024); \
    iv2 = *(const bf16x8*)(vs_ + 2048);  iv3 = *(const bf16x8*)(vs_ + 3072); \
} while (0)

#define STW_IMG(KB, VB) do { \
    char* kd_ = (char*)(KB) + woff + lby; \
    char* vd_ = (char*)(VB) + woff + lby; \
    *(bf16x8*)(kd_ +    0) = ik0;  *(bf16x8*)(kd_ + 1024) = ik1; \
    *(bf16x8*)(kd_ + 2048) = ik2;  *(bf16x8*)(kd_ + 3072) = ik3; \
    *(bf16x8*)(vd_ +    0) = iv0;  *(bf16x8*)(vd_ + 1024) = iv1; \
    *(bf16x8*)(vd_ + 2048) = iv2;  *(bf16x8*)(vd_ + 3072) = iv3; \
} while (0)

#define LOAD_M(K0, R0, R1, R2, R3) do { \
    const float* mb_ = mbase + (K0) + lg * 4; \
    R0 = *(const float4*)(mb_ +  0);  R1 = *(const float4*)(mb_ + 16); \
    R2 = *(const float4*)(mb_ + 32);  R3 = *(const float4*)(mb_ + 48); \
} while (0)

#define COMPUTE(KB, VB, M0, M1, M2, M3) do { \
    f32x4 sacc[4]; \
    _Pragma("unroll") for (int m = 0; m < 4; ++m) sacc[m] = (f32x4){0.f,0.f,0.f,0.f}; \
    __builtin_amdgcn_s_setprio(1); \
    _Pragma("unroll") for (int m = 0; m < 4; ++m) { \
        _Pragma("unroll") for (int c = 0; c < 4; ++c) { \
            bf16x8 af = *(bf16x8*)&KB[(m * 16 + lq) * 128 + ((c * 32 + lg * 8) ^ swzL)]; \
            sacc[m] = __builtin_amdgcn_mfma_f32_16x16x32_bf16(af, qf[c], sacc[m], 0, 0, 0); \
        } \
    } \
    __builtin_amdgcn_s_setprio(0); \
    float mk_[16] = { M0.x, M0.y, M0.z, M0.w,  M1.x, M1.y, M1.z, M1.w, \
                      M2.x, M2.y, M2.z, M2.w,  M3.x, M3.y, M3.z, M3.w }; \
    float sv[4][4], tmax = -1e30f; \
    _Pragma("unroll") for (int m = 0; m < 4; ++m) \
        _Pragma("unroll") for (int r = 0; r < 4; ++r) { \
            sv[m][r] = sacc[m][r] * scale; \
            tmax = fmaxf(tmax, sv[m][r]); \
        } \
    tmax = fmaxf(tmax, __shfl_xor(tmax, 16)); \
    tmax = fmaxf(tmax, __shfl_xor(tmax, 32)); \
    if (!__all(tmax - m_run <= 8.f)) { \
        const float mnew  = fmaxf(m_run, tmax); \
        const float alpha = __expf(m_run - mnew); \
        m_run = mnew;  z_part *= alpha;  s_part *= alpha; \
        float alr[4]; \
        _Pragma("unroll") for (int r = 0; r < 4; ++r) alr[r] = __shfl(alpha, lg * 4 + r); \
        _Pragma("unroll") for (int n = 0; n < 8; ++n) \
            _Pragma("unroll") for (int r = 0; r < 4; ++r) oacc[n][r] *= alr[r]; \
    } \
    float zl = 0.f, sl = 0.f, pm[4][4]; \
    _Pragma("unroll") for (int m = 0; m < 4; ++m) \
        _Pragma("unroll") for (int r = 0; r < 4; ++r) { \
            float p = __expf(sv[m][r] - m_run); \
            zl += p; \
            float pq = p * mk_[m * 4 + r]; \
            sl += pq;  pm[m][r] = pq; \
        } \
    z_part += zl;  s_part += sl; \
    _Pragma("unroll") for (int m = 0; m < 4; ++m) \
        *(bf16x4*)&Ps[w][lq][m * 16 + lg * 4] = \
            (bf16x4){ (__bf16)pm[m][0], (__bf16)pm[m][1], (__bf16)pm[m][2], (__bf16)pm[m][3] }; \
    __builtin_amdgcn_s_setprio(1); \
    _Pragma("unroll") for (int kc = 0; kc < 2; ++kc) { \
        bf16x8 pa = *(bf16x8*)&Ps[w][lq][kc * 32 + lg * 8]; \
        _Pragma("unroll") for (int n = 0; n < 8; ++n) { \
            bf16x8 vv = *(bf16x8*)&VB[(n * 16 + lq) * 64 + ((kc * 32 + lg * 8) ^ swzL)]; \
            oacc[n] = __builtin_amdgcn_mfma_f32_16x16x32_bf16(pa, vv, oacc[n], 0, 0, 0); \
        } \
    } \
    __builtin_amdgcn_s_setprio(0); \
} while (0)

// Barrier WITHOUT vmcnt drain: ds ops drained (cross-wave visibility), VMEM
// loads (register-private: img regs + mask regs) stay in flight across it.
#define SOFT_BARRIER() do { \
    asm volatile("s_waitcnt lgkmcnt(0)" ::: "memory"); \
    __builtin_amdgcn_sched_barrier(0); \
    __builtin_amdgcn_s_barrier(); \
    __builtin_amdgcn_sched_barrier(0); \
} while (0)

// iter kt: STW img(kt+1)->other; load img(kt+2)->regs; mask(kt+1)->ML; compute(kt); barrier
#define ITER(KT, KBc, VBc, KBn, VBn, MU0,MU1,MU2,MU3, ML0,ML1,ML2,ML3) do { \
    if ((KT) + 1 < NT) STW_IMG(KBn, VBn); \
    if ((KT) + 2 < NT) LOAD_IMG((KT) + 2); \
    if ((KT) + 1 < NT) LOAD_M(((KT) + 1) * KBLK, ML0, ML1, ML2, ML3); \
    COMPUTE(KBc, VBc, MU0, MU1, MU2, MU3); \
    if ((KT) + 1 < NT) SOFT_BARRIER(); \
} while (0)

__global__ __launch_bounds__(256, 2) void
attn_main(const float* __restrict__ Qg, const unsigned short* __restrict__ Kimg,
          const unsigned short* __restrict__ Vimg, const float* __restrict__ Mg,
          float* __restrict__ Og)
{
    const int wg = ((blockIdx.x & 7) << 7) | (blockIdx.x >> 3);   // XCD swizzle
    const int b  = wg >> 5;
    const int q0 = (wg & 31) * QBLK;

    const int t  = threadIdx.x;
    const int w  = t >> 6;
    const int l  = t & 63;
    const int lq = l & 15;
    const int lg = l >> 4;
    const int swzL = (lq & 7) << 3;
    const int woff = w * 4096;        // wave's quarter of the 16KB tile image
    const int lby  = l * 16;          // lane byte offset within 1KB chunk

    __shared__ __align__(16) unsigned short Kb0[64 * 128];
    __shared__ __align__(16) unsigned short Kb1[64 * 128];
    __shared__ __align__(16) unsigned short Vb0[128 * 64];
    __shared__ __align__(16) unsigned short Vb1[128 * 64];
    __shared__ __align__(16) unsigned short Ps[4][16][72];

    const char* KimgB = (const char*)Kimg;
    const char* VimgB = (const char*)Vimg;

    const int qrow = q0 + w * 16 + lq;

    bf16x8 qf[4];
    {
        const float* qb = Qg + ((size_t)b * NQL + qrow) * DH;
        #pragma unroll
        for (int c = 0; c < 4; ++c) {
            const float* p = qb + c * 32 + lg * 8;
            float4 x = *(const float4*)(p);
            float4 y = *(const float4*)(p + 4);
            qf[c] = (bf16x8){ (__bf16)x.x, (__bf16)x.y, (__bf16)x.z, (__bf16)x.w,
                              (__bf16)y.x, (__bf16)y.y, (__bf16)y.z, (__bf16)y.w };
        }
    }

    float m_run = -1e30f, z_part = 0.f, s_part = 0.f;
    f32x4 oacc[8];
    #pragma unroll
    for (int n = 0; n < 8; ++n) oacc[n] = (f32x4){0.f, 0.f, 0.f, 0.f};

    const float* mbase = Mg + ((size_t)b * NQL + qrow) * NKL;
    const float scale = 0.08838834764831845f;

    // staging registers (named -> no scratch)
    bf16x8 ik0, ik1, ik2, ik3, iv0, iv1, iv2, iv3;
    float4 mA0, mA1, mA2, mA3, mB0, mB1, mB2, mB3;

    // prologue: buf0 <- tile 0; regs <- tile 1; mask(0) in mA
    LOAD_IMG(0);
    LOAD_M(0, mA0, mA1, mA2, mA3);
    STW_IMG(Kb0, Vb0);
    LOAD_IMG(1);
    SOFT_BARRIER();

    for (int kt = 0; kt < NT; kt += 2) {
        ITER(kt,     Kb0, Vb0, Kb1, Vb1, mA0,mA1,mA2,mA3, mB0,mB1,mB2,mB3);
        ITER(kt + 1, Kb1, Vb1, Kb0, Vb0, mB0,mB1,mB2,mB3, mA0,mA1,mA2,mA3);
    }

    // epilogue
    float z = z_part + __shfl_xor(z_part, 16);
    z += __shfl_xor(z, 32);
    float s = s_part + __shfl_xor(s_part, 16);
    s += __shfl_xor(s, 32);
    const float inv = 1.f / (s + EPS * z);
    float ivr[4];
    #pragma unroll
    for (int r = 0; r < 4; ++r) ivr[r] = __shfl(inv, lg * 4 + r);

    float* ob = Og + ((size_t)b * NQL + q0 + w * 16) * DH;
    #pragma unroll
    for (int n = 0; n < 8; ++n)
        #pragma unroll
        for (int r = 0; r < 4; ++r)
            ob[(size_t)(lg * 4 + r) * DH + n * 16 + lq] = oacc[n][r] * ivr[r];
}

// =============================== fallback (round-3 kernel) ===============================
__global__ __launch_bounds__(256, 3) void
attn_fb(const float* __restrict__ Qg, const float* __restrict__ Kg,
        const float* __restrict__ Vg, const float* __restrict__ Mg,
        float* __restrict__ Og)
{
    const int wg = ((blockIdx.x & 7) << 7) | (blockIdx.x >> 3);
    const int b  = wg >> 5;
    const int q0 = (wg & 31) * QBLK;
    const int t  = threadIdx.x;
    const int w  = t >> 6;
    const int l  = t & 63;
    const int lq = l & 15;
    const int lg = l >> 4;
    __shared__ __align__(16) unsigned short Ks[64 * 128];
    __shared__ __align__(16) unsigned short Vs[128 * 64];
    __shared__ __align__(16) unsigned short Ps[4][16][72];
    const int rK   = t >> 2;
    const int cK   = (t & 3) * 32;
    const int dV   = t >> 1;
    const int khV  = t & 1;
    const int swzK = (rK & 7) << 3;
    const int swzV = (dV & 7) << 3;
    const int swzL = (lq & 7) << 3;
    const int qrow = q0 + w * 16 + lq;
    bf16x8 qf[4];
    {
        const float* qb = Qg + ((size_t)b * NQL + qrow) * DH;
        #pragma unroll
        for (int c = 0; c < 4; ++c) {
            const float* p = qb + c * 32 + lg * 8;
            float4 x = *(const float4*)(p);
            float4 y = *(const float4*)(p + 4);
            qf[c] = (bf16x8){ (__bf16)x.x, (__bf16)x.y, (__bf16)x.z, (__bf16)x.w,
                              (__bf16)y.x, (__bf16)y.y, (__bf16)y.z, (__bf16)y.w };
        }
    }
    float m_run = -1e30f, z_part = 0.f, s_part = 0.f;
    f32x4 oacc[8];
    #pragma unroll
    for (int n = 0; n < 8; ++n) oacc[n] = (f32x4){0.f, 0.f, 0.f, 0.f};
    const float* kbase = Kg + (size_t)b * NKL * DH;
    const float* vbase = Vg + (size_t)b * NKL * DH;
    const float* mbase = Mg + ((size_t)b * NQL + qrow) * NKL;
    const float scale = 0.08838834764831845f;
    for (int kt = 0; kt < NT; ++kt) {
        const int k0 = kt * KBLK;
        float mkf[16];
        {
            const float* mb = mbase + k0 + lg * 4;
            #pragma unroll
            for (int m = 0; m < 4; ++m) {
                float4 x = *(const float4*)(mb + m * 16);
                mkf[m*4+0]=x.x; mkf[m*4+1]=x.y; mkf[m*4+2]=x.z; mkf[m*4+3]=x.w;
            }
        }
        __syncthreads();
        {
            const float* kb = kbase + (size_t)(k0 + rK) * DH + cK;
            #pragma unroll
            for (int i = 0; i < 4; ++i) {
                float4 a = *(const float4*)(kb + i * 8);
                float4 c = *(const float4*)(kb + i * 8 + 4);
                *(bf16x8*)&Ks[rK * 128 + ((cK + i * 8) ^ swzK)] =
                    (bf16x8){ (__bf16)a.x, (__bf16)a.y, (__bf16)a.z, (__bf16)a.w,
                              (__bf16)c.x, (__bf16)c.y, (__bf16)c.z, (__bf16)c.w };
            }
            const float* vb = vbase + (size_t)(k0 + khV * 32) * DH + dV;
            #pragma unroll
            for (int i = 0; i < 4; ++i) {
                bf16x8 o;
                #pragma unroll
                for (int j = 0; j < 8; ++j) o[j] = (__bf16)vb[(i * 8 + j) * DH];
                *(bf16x8*)&Vs[dV * 64 + (((khV << 5) + i * 8) ^ swzV)] = o;
            }
        }
        __syncthreads();
        f32x4 sacc[4];
        #pragma unroll
        for (int m = 0; m < 4; ++m) sacc[m] = (f32x4){0.f,0.f,0.f,0.f};
        #pragma unroll
        for (int m = 0; m < 4; ++m)
            #pragma unroll
            for (int c = 0; c < 4; ++c) {
                bf16x8 af = *(bf16x8*)&Ks[(m * 16 + lq) * 128 + ((c * 32 + lg * 8) ^ swzL)];
                sacc[m] = __builtin_amdgcn_mfma_f32_16x16x32_bf16(af, qf[c], sacc[m], 0, 0, 0);
            }
        float sv[4][4], tmax = -1e30f;
        #pragma unroll
        for (int m = 0; m < 4; ++m)
            #pragma unroll
            for (int r = 0; r < 4; ++r) {
                sv[m][r] = sacc[m][r] * scale;
                tmax = fmaxf(tmax, sv[m][r]);
            }
        tmax = fmaxf(tmax, __shfl_xor(tmax, 16));
        tmax = fmaxf(tmax, __shfl_xor(tmax, 32));
        if (!__all(tmax - m_run <= 8.f)) {
            const float mnew  = fmaxf(m_run, tmax);
            const float alpha = __expf(m_run - mnew);
            m_run = mnew; z_part *= alpha; s_part *= alpha;
            float alr[4];
            #pragma unroll
            for (int r = 0; r < 4; ++r) alr[r] = __shfl(alpha, lg * 4 + r);
            #pragma unroll
            for (int n = 0; n < 8; ++n)
                #pragma unroll
                for (int r = 0; r < 4; ++r) oacc[n][r] *= alr[r];
        }
        float zl = 0.f, sl = 0.f, pm[4][4];
        #pragma unroll
        for (int m = 0; m < 4; ++m)
            #pragma unroll
            for (int r = 0; r < 4; ++r) {
                float p = __expf(sv[m][r] - m_run);
                zl += p;
                float pq = p * mkf[m * 4 + r];
                sl += pq; pm[m][r] = pq;
            }
        z_part += zl; s_part += sl;
        #pragma unroll
        for (int m = 0; m < 4; ++m)
            *(bf16x4*)&Ps[w][lq][m * 16 + lg * 4] =
                (bf16x4){ (__bf16)pm[m][0], (__bf16)pm[m][1], (__bf16)pm[m][2], (__bf16)pm[m][3] };
        #pragma unroll
        for (int kc = 0; kc < 2; ++kc) {
            bf16x8 pa = *(bf16x8*)&Ps[w][lq][kc * 32 + lg * 8];
            #pragma unroll
            for (int n = 0; n < 8; ++n) {
                bf16x8 vv = *(bf16x8*)&Vs[(n * 16 + lq) * 64 + ((kc * 32 + lg * 8) ^ swzL)];
                oacc[n] = __builtin_amdgcn_mfma_f32_16x16x32_bf16(pa, vv, oacc[n], 0, 0, 0);
            }
        }
    }
    float z = z_part + __shfl_xor(z_part, 16);
    z += __shfl_xor(z, 32);
    float s = s_part + __shfl_xor(s_part, 16);
    s += __shfl_xor(s, 32);
    const float inv = 1.f / (s + EPS * z);
    float ivr[4];
    #pragma unroll
    for (int r = 0; r < 4; ++r) ivr[r] = __shfl(inv, lg * 4 + r);
    float* ob = Og + ((size_t)b * NQL + q0 + w * 16) * DH;
    #pragma unroll
    for (int n = 0; n < 8; ++n)
        #pragma unroll
        for (int r = 0; r < 4; ++r)
            ob[(size_t)(lg * 4 + r) * DH + n * 16 + lq] = oacc[n][r] * ivr[r];
}

extern "C" void kernel_launch(void* const* d_in, const int* in_sizes, int n_in,
                              void* d_out, int out_size, void* d_ws, size_t ws_size,
                              hipStream_t stream)
{
    (void)in_sizes; (void)n_in; (void)out_size;
    const float* Q = (const float*)d_in[0];
    const float* K = (const float*)d_in[1];
    const float* V = (const float*)d_in[2];
    const float* M = (const float*)d_in[3];
    float* O = (float*)d_out;

    const size_t imgElems = (size_t)NB * NKL * DH;
    const size_t need     = 2 * imgElems * sizeof(unsigned short);

    if (ws_size >= need) {
        unsigned short* Kimg = (unsigned short*)d_ws;
        unsigned short* Vimg = Kimg + imgElems;
        prep_kv<<<dim3(2 * NB * NT), 256, 0, stream>>>(K, V, Kimg, Vimg);
        attn_main<<<dim3(NB * (NQL / QBLK)), 256, 0, stream>>>(Q, Kimg, Vimg, M, O);
    } else {
        attn_fb<<<dim3(NB * (NQL / QBLK)), 256, 0, stream>>>(Q, K, V, M, O);
    }
}